// Round 6
// baseline (899.661 us; speedup 1.0000x reference)
//
#include <hip/hip_runtime.h>
#include <math.h>

// NeuralstackOnly (R6): 3-stage pipeline
//  K1 pop_fused:  g=elu(cos(le,x_t)) + latch scan + pop=elu(cos(sp,latch))
//                 chunked two-phase LDS matrix reduction, block per b
//  K2 ptr_scan:   pointer recurrence, 4 batches/block (2 lane-groups x 2
//                 register-chains), readlane tree tail; emits A,B,W[b,t,96]
//  K3 stack_affine: stz' = A*stz + B*xvz, out = sum W*stz + ZO*pop
//                 pure-global reads (L2 broadcast), depth-2 prefetch
// B=128, T=256, D=256, NSTK=32.

#define NSTK 32
#define DDIM 256
#define ZO 1e-6f
#define EPSC 1e-8f
#define PEPS 1e-12f
#define CHUNK 32
#define MAXT 1024

__device__ __forceinline__ float elu_f(float c) {
    return (c > 0.f) ? c : expm1f(c);
}

// DPP cross-lane helpers (verified R4/R5)
__device__ __forceinline__ float dpp_xor1(float x) {
    return __int_as_float(__builtin_amdgcn_update_dpp(0, __float_as_int(x), 0xB1, 0xF, 0xF, true));
}
__device__ __forceinline__ float dpp_xor2(float x) {
    return __int_as_float(__builtin_amdgcn_update_dpp(0, __float_as_int(x), 0x4E, 0xF, 0xF, true));
}
__device__ __forceinline__ float dpp_halfmirror(float x) {
    return __int_as_float(__builtin_amdgcn_update_dpp(0, __float_as_int(x), 0x141, 0xF, 0xF, true));
}
__device__ __forceinline__ float dpp_mirror(float x) {
    return __int_as_float(__builtin_amdgcn_update_dpp(0, __float_as_int(x), 0x140, 0xF, 0xF, true));
}
__device__ __forceinline__ float rdlane(float v, int l) {
    return __int_as_float(__builtin_amdgcn_readlane(__float_as_int(v), l));
}

// ---------------- K1: fused gates + latch scan -> pop[B,T] ------------------
__launch_bounds__(256, 1)
__global__ void pop_fused_kernel(const float* __restrict__ x,
                                 const float* __restrict__ should_pop,
                                 const float* __restrict__ latch_enable,
                                 const float* __restrict__ latch_init,
                                 float* __restrict__ pop_out, int T) {
    const int b = blockIdx.x;
    const int tid = threadIdx.x;               // = d
    const int wave = tid >> 6, lane = tid & 63;
    __shared__ float part[256 * 66];           // [d][64 partials], pad->66
    __shared__ float red4[4][64];
    __shared__ float g_s[CHUNK];

    const float sp_d = should_pop[tid];
    const float le_d = latch_enable[tid];
    float a0 = sp_d * sp_d, a1 = le_d * le_d;
#pragma unroll
    for (int off = 32; off >= 1; off >>= 1) {
        a0 += __shfl_xor(a0, off, 64);
        a1 += __shfl_xor(a1, off, 64);
    }
    if (lane == 0) { red4[wave][0] = a0; red4[wave][1] = a1; }
    __syncthreads();
    const float an_sp = fmaxf(sqrtf(red4[0][0] + red4[1][0] + red4[2][0] + red4[3][0]), EPSC);
    const float an_le = fmaxf(sqrtf(red4[0][1] + red4[1][1] + red4[2][1] + red4[3][1]), EPSC);
    __syncthreads();

    float l = latch_init[(size_t)b * DDIM + tid];
    const float* xb = x + (size_t)b * T * DDIM + tid;
    const int p = tid & 63, dg = tid >> 6;     // reduce assignment

    for (int c = 0; c < T; c += CHUNK) {
        float xv[CHUNK];
#pragma unroll
        for (int i = 0; i < CHUNK; i++) xv[i] = xb[(size_t)(c + i) * DDIM];

        // ---- Phase A: g_t from x only ----
#pragma unroll
        for (int i = 0; i < CHUNK; i++) {
            part[tid * 66 + 2 * i] = le_d * xv[i];
            part[tid * 66 + 2 * i + 1] = xv[i] * xv[i];
        }
        __syncthreads();
        {
            float s0 = 0.f, s1 = 0.f, s2 = 0.f, s3 = 0.f;
#pragma unroll
            for (int k = 0; k < 64; k += 4) {
                s0 += part[(dg * 64 + k) * 66 + p];
                s1 += part[(dg * 64 + k + 1) * 66 + p];
                s2 += part[(dg * 64 + k + 2) * 66 + p];
                s3 += part[(dg * 64 + k + 3) * 66 + p];
            }
            red4[wave][p] = (s0 + s1) + (s2 + s3);
        }
        __syncthreads();
        if (tid < CHUNK) {
            const float d0 = red4[0][2 * tid] + red4[1][2 * tid] + red4[2][2 * tid] + red4[3][2 * tid];
            const float d1 = red4[0][2 * tid + 1] + red4[1][2 * tid + 1] + red4[2][2 * tid + 1] + red4[3][2 * tid + 1];
            g_s[tid] = elu_f(d0 / (an_le * fmaxf(sqrtf(d1), EPSC)));
        }
        __syncthreads();

        // ---- Phase B: latch updates + pop partials ----
#pragma unroll
        for (int i = 0; i < CHUNK; i++) {
            part[tid * 66 + 2 * i] = sp_d * l;       // latch ENTERING step c+i
            part[tid * 66 + 2 * i + 1] = l * l;
            l = fmaf(g_s[i], xv[i] - l, l);
        }
        __syncthreads();
        {
            float s0 = 0.f, s1 = 0.f, s2 = 0.f, s3 = 0.f;
#pragma unroll
            for (int k = 0; k < 64; k += 4) {
                s0 += part[(dg * 64 + k) * 66 + p];
                s1 += part[(dg * 64 + k + 1) * 66 + p];
                s2 += part[(dg * 64 + k + 2) * 66 + p];
                s3 += part[(dg * 64 + k + 3) * 66 + p];
            }
            red4[wave][p] = (s0 + s1) + (s2 + s3);
        }
        __syncthreads();
        if (tid < CHUNK) {
            const float d0 = red4[0][2 * tid] + red4[1][2 * tid] + red4[2][2 * tid] + red4[3][2 * tid];
            const float d1 = red4[0][2 * tid + 1] + red4[1][2 * tid + 1] + red4[2][2 * tid + 1] + red4[3][2 * tid + 1];
            pop_out[(size_t)b * T + c + tid] = elu_f(d0 / (an_sp * fmaxf(sqrtf(d1), EPSC)));
        }
        __syncthreads();   // protect part/red4 before next chunk
    }
}

// ---------------- K2: pointer recurrence, 4 batches per block ---------------
// coef layout per (b,t): [A[32] | B[32] | W[32]]
__launch_bounds__(64, 1)
__global__ void ptr_scan_kernel(const float* __restrict__ pop_arr,  // [B,T]
                                const float* __restrict__ sharpen_ptr,
                                float* __restrict__ coef,           // [B,T,96]
                                int T) {
    const int blk = blockIdx.x;
    const int tid = threadIdx.x;
    const int n = tid & 31;
    const int grp = tid >> 5;                  // 0/1
    const int bA = blk * 4 + grp;
    const int bB = blk * 4 + 2 + grp;
    const float sharpen = sharpen_ptr[0];
    const bool sharp5 = (sharpen == 5.0f);

    __shared__ float pops[4 * MAXT];
    for (int i = tid; i < 4 * T; i += 64) pops[i] = pop_arr[(size_t)blk * 4 * T + i];
    __syncthreads();
    const float* popA = pops + grp * T;
    const float* popB = pops + (2 + grp) * T;
    float* cfA = coef + (size_t)bA * T * 96;
    float* cfB = coef + (size_t)bB * T * 96;

    float uA = (n == 0) ? 1.0f : ZO, iA = 1.0f;
    float uB = uA, iB = 1.0f;

    for (int t = 0; t < T; t++) {
        const float poA = popA[t], poB = popB[t];
        const float psA = 1.0f - poA, psB = 1.0f - poB;
        const float upA = __shfl(uA, (n + 31) & 31, 32);
        const float upB = __shfl(uB, (n + 31) & 31, 32);
        const float unA = __shfl(uA, (n + 1) & 31, 32);
        const float unB = __shfl(uB, (n + 1) & 31, 32);
        const float rA = fmaf(psA, upA, poA * unA);
        const float rB = fmaf(psB, upB, poB * unB);
        const float qA = fmaxf(rA * iA, PEPS);
        const float qB = fmaxf(rB * iB, PEPS);
        float nuA, nuB;
        if (sharp5) {
            const float a2 = qA * qA, b2 = qB * qB;
            nuA = a2 * a2 * qA; nuB = b2 * b2 * qB;
        } else {
            nuA = exp2f(sharpen * log2f(qA));
            nuB = exp2f(sharpen * log2f(qB));
        }
        // sum over 32 slots: 4 DPP pair-adds (all lanes get 16-group sums)
        float sA = nuA, sB = nuB;
        sA += dpp_xor1(sA);       sB += dpp_xor1(sB);
        sA += dpp_xor2(sA);       sB += dpp_xor2(sB);
        sA += dpp_halfmirror(sA); sB += dpp_halfmirror(sB);
        sA += dpp_mirror(sA);     sB += dpp_mirror(sB);
        // cross-16 via readlane (avoids ds_swizzle latency)
        const float tA = (tid < 32) ? (rdlane(sA, 15) + rdlane(sA, 31))
                                    : (rdlane(sA, 47) + rdlane(sA, 63));
        const float tB = (tid < 32) ? (rdlane(sB, 15) + rdlane(sB, 31))
                                    : (rdlane(sB, 47) + rdlane(sB, 63));
        const float ivA = 1.0f / fmaxf(tA, EPSC);
        const float ivB = 1.0f / fmaxf(tB, EPSC);
        // coefficient emission (off the recurrence chain)
        const float pA = uA * iA, ppA = upA * iA, pnA = nuA * ivA;
        const float pB = uB * iB, ppB = upB * iB, pnB = nuB * ivB;
        float* rowA = cfA + (size_t)t * 96;
        float* rowB = cfB + (size_t)t * 96;
        rowA[n]      = fmaf(-psA, ppA, fmaf(-poA, pA, 1.0f));  // A = 1-B-pop*p
        rowA[32 + n] = psA * ppA;                              // Bc = push*pp
        rowA[64 + n] = poA * pnA;                              // W = pop*pnew
        rowB[n]      = fmaf(-psB, ppB, fmaf(-poB, pB, 1.0f));
        rowB[32 + n] = psB * ppB;
        rowB[64 + n] = poB * pnB;
        uA = nuA; iA = ivA;
        uB = nuB; iB = ivB;
    }
}

// ---------------- K3: affine stack recurrence + readout ---------------------
// grid (D/16, B), 64 threads: 16 dsub x 4 ng (8 slots each). No LDS.
__launch_bounds__(64, 4)
__global__ void stack_affine_kernel(const float* __restrict__ x,       // [B,T,D]
                                    const float* __restrict__ coef,    // [B,T,96]
                                    const float* __restrict__ pop_arr, // [B,T]
                                    float* __restrict__ out,           // [B,T,D]
                                    int T) {
    const int b = blockIdx.y;
    const int dtile = blockIdx.x;              // 0..15
    const int lane = threadIdx.x;
    const int dsub = lane & 15;
    const int ng = lane >> 4;                  // slots ng*8..ng*8+7

    const float* cfb = coef + (size_t)b * T * 96 + ng * 8;
    const float* xb = x + (size_t)b * T * DDIM + dtile * 16 + dsub;
    const float* popb = pop_arr + (size_t)b * T;
    float* ob = out + (size_t)b * T * DDIM + dtile * 16 + dsub;

    float4 A0[2], A1[2], B0[2], B1[2], W0[2], W1[2];
    float xvv[2], pv[2];

    auto ld = [&](int t, int s) {
        const float* c = cfb + (size_t)t * 96;
        A0[s] = *(const float4*)(c);
        A1[s] = *(const float4*)(c + 4);
        B0[s] = *(const float4*)(c + 32);
        B1[s] = *(const float4*)(c + 36);
        W0[s] = *(const float4*)(c + 64);
        W1[s] = *(const float4*)(c + 68);
        xvv[s] = xb[(size_t)t * DDIM];
        pv[s] = popb[t];
    };

    float stz[8];
#pragma unroll
    for (int i = 0; i < 8; i++) stz[i] = 0.f;   // st = ZO -> stz = 0

    ld(0, 0);
    if (T > 1) ld(1, 1);

    for (int t = 0; t < T; t++) {
        const int s = t & 1;
        const float xvz = xvv[s] - ZO;
        float acc;
        stz[0] = fmaf(A0[s].x, stz[0], B0[s].x * xvz); acc  = W0[s].x * stz[0];
        stz[1] = fmaf(A0[s].y, stz[1], B0[s].y * xvz); acc = fmaf(W0[s].y, stz[1], acc);
        stz[2] = fmaf(A0[s].z, stz[2], B0[s].z * xvz); acc = fmaf(W0[s].z, stz[2], acc);
        stz[3] = fmaf(A0[s].w, stz[3], B0[s].w * xvz); acc = fmaf(W0[s].w, stz[3], acc);
        stz[4] = fmaf(A1[s].x, stz[4], B1[s].x * xvz); acc = fmaf(W1[s].x, stz[4], acc);
        stz[5] = fmaf(A1[s].y, stz[5], B1[s].y * xvz); acc = fmaf(W1[s].y, stz[5], acc);
        stz[6] = fmaf(A1[s].z, stz[6], B1[s].z * xvz); acc = fmaf(W1[s].z, stz[6], acc);
        stz[7] = fmaf(A1[s].w, stz[7], B1[s].w * xvz); acc = fmaf(W1[s].w, stz[7], acc);
        const float popv = pv[s];
        if (t + 2 < T) ld(t + 2, s);           // depth-2 prefetch into freed buf
        acc += __shfl_xor(acc, 16, 64);
        acc += __shfl_xor(acc, 32, 64);
        if (ng == 0) ob[(size_t)t * DDIM] = fmaf(ZO, popv, acc);
    }
}

// ---------------- Fallback: monolithic kernel (correct, slower) -------------
__launch_bounds__(256, 1)
__global__ void neuralstack_kernel(const float* __restrict__ x,
                                   const float* __restrict__ should_pop,
                                   const float* __restrict__ sharpen_ptr,
                                   const float* __restrict__ latch_enable,
                                   const float* __restrict__ latch_init,
                                   float* __restrict__ out,
                                   int T) {
    const int b = blockIdx.x;
    const int tid = threadIdx.x;
    const int wave = tid >> 6;
    const int lane = tid & 63;
    __shared__ float red[2][16];
    const float sp_d = should_pop[tid];
    const float le_d = latch_enable[tid];
    const float sharpen = sharpen_ptr[0];
    float latch = latch_init[(size_t)b * DDIM + tid];
    float a0 = sp_d * sp_d, a1 = le_d * le_d;
#pragma unroll
    for (int off = 32; off >= 1; off >>= 1) {
        a0 += __shfl_xor(a0, off, 64);
        a1 += __shfl_xor(a1, off, 64);
    }
    if (lane == 0) { red[0][wave * 4] = a0; red[0][wave * 4 + 1] = a1; }
    __syncthreads();
    const float an_sp = fmaxf(sqrtf(red[0][0] + red[0][4] + red[0][8] + red[0][12]), EPSC);
    const float an_le = fmaxf(sqrtf(red[0][1] + red[0][5] + red[0][9] + red[0][13]), EPSC);
    __syncthreads();
    float st[NSTK], ptr[NSTK];
#pragma unroll
    for (int n = 0; n < NSTK; n++) { st[n] = ZO; ptr[n] = (n == 0) ? 1.0f : ZO; }
    const float* xb = x + (size_t)b * T * DDIM + tid;
    float* ob = out + (size_t)b * T * DDIM + tid;
    const bool sharp5 = (sharpen == 5.0f);
    float inp = xb[0];
    for (int t = 0; t < T; t++) {
        const int tn = (t + 1 < T) ? (t + 1) : (T - 1);
        const float inp_next = xb[(size_t)tn * DDIM];
        float r0 = sp_d * latch, r1 = latch * latch, r2 = le_d * inp, r3 = inp * inp;
#pragma unroll
        for (int off = 32; off >= 1; off >>= 1) {
            r0 += __shfl_xor(r0, off, 64);
            r1 += __shfl_xor(r1, off, 64);
            r2 += __shfl_xor(r2, off, 64);
            r3 += __shfl_xor(r3, off, 64);
        }
        const int buf = t & 1;
        if (lane == 0) {
            red[buf][wave * 4] = r0; red[buf][wave * 4 + 1] = r1;
            red[buf][wave * 4 + 2] = r2; red[buf][wave * 4 + 3] = r3;
        }
        __syncthreads();
        const float s0 = red[buf][0] + red[buf][4] + red[buf][8] + red[buf][12];
        const float s1 = red[buf][1] + red[buf][5] + red[buf][9] + red[buf][13];
        const float s2 = red[buf][2] + red[buf][6] + red[buf][10] + red[buf][14];
        const float s3 = red[buf][3] + red[buf][7] + red[buf][11] + red[buf][15];
        const float pop = elu_f(s0 / (an_sp * fmaxf(sqrtf(s1), EPSC)));
        const float push = 1.0f - pop;
        const float g = elu_f(s2 / (an_le * fmaxf(sqrtf(s3), EPSC)));
        float q[NSTK];
#pragma unroll
        for (int n = 0; n < NSTK; n++) {
            const float pp = ptr[(n + NSTK - 1) & (NSTK - 1)];
            const float pn = ptr[(n + 1) & (NSTK - 1)];
            q[n] = fmaxf(push * pp + pop * pn, PEPS);
        }
        if (sharp5) {
#pragma unroll
            for (int n = 0; n < NSTK; n++) { const float v = q[n], v2 = v * v; q[n] = v2 * v2 * v; }
        } else {
#pragma unroll
            for (int n = 0; n < NSTK; n++) q[n] = exp2f(sharpen * log2f(q[n]));
        }
        float qa = 0.f, qb = 0.f, qc = 0.f, qd = 0.f;
#pragma unroll
        for (int n = 0; n < NSTK; n += 4) { qa += q[n]; qb += q[n+1]; qc += q[n+2]; qd += q[n+3]; }
        const float inv = 1.0f / fmaxf((qa + qb) + (qc + qd), EPSC);
        float sacc = 0.f;
#pragma unroll
        for (int n = 0; n < NSTK; n++) {
            const float pp = ptr[(n + NSTK - 1) & (NSTK - 1)];
            const float pc_ = ptr[n];
            const float ns = push * (st[n] + pp * (inp - st[n])) + pop * (st[n] + pc_ * (ZO - st[n]));
            st[n] = ns;
            sacc += ns * (q[n] * inv);
        }
#pragma unroll
        for (int n = 0; n < NSTK; n++) ptr[n] = q[n] * inv;
        ob[(size_t)t * DDIM] = pop * sacc;
        latch = fmaf(g, inp - latch, latch);
        inp = inp_next;
    }
}

extern "C" void kernel_launch(void* const* d_in, const int* in_sizes, int n_in,
                              void* d_out, int out_size, void* d_ws, size_t ws_size,
                              hipStream_t stream) {
    const float* x = (const float*)d_in[0];
    const float* should_pop = (const float*)d_in[1];
    const float* sharpen_ptr = (const float*)d_in[2];
    const float* latch_enable = (const float*)d_in[3];
    const float* latch_init = (const float*)d_in[4];
    float* out = (float*)d_out;

    const int D = in_sizes[1];                 // 256
    const int B = in_sizes[4] / D;             // 128
    const int T = in_sizes[0] / in_sizes[4];   // 256
    (void)n_in; (void)out_size;

    const size_t BT = (size_t)B * T;
    const size_t off_pop = 0;
    const size_t off_coef = BT;                // floats (128 KB aligned)
    const size_t need_floats = off_coef + BT * 96;

    if (ws_size < need_floats * sizeof(float) || D != DDIM ||
        (T % CHUNK) != 0 || (B % 4) != 0 || T > MAXT) {
        neuralstack_kernel<<<B, 256, 0, stream>>>(x, should_pop, sharpen_ptr,
                                                  latch_enable, latch_init, out, T);
        return;
    }

    float* ws = (float*)d_ws;
    float* pop = ws + off_pop;
    float* coef = ws + off_coef;

    pop_fused_kernel<<<B, 256, 0, stream>>>(x, should_pop, latch_enable,
                                            latch_init, pop, T);
    ptr_scan_kernel<<<B / 4, 64, 0, stream>>>(pop, sharpen_ptr, coef, T);
    stack_affine_kernel<<<dim3(DDIM / 16, B), 64, 0, stream>>>(x, coef, pop, out, T);
}

// Round 7
// 308.348 us; speedup vs baseline: 2.9177x; 2.9177x over previous
//
#include <hip/hip_runtime.h>
#include <math.h>

// NeuralstackOnly (R7): 3-stage pipeline
//  K1 pop_fused:  g=elu(cos(le,x_t)) + latch scan + pop=elu(cos(sp,latch))
//  K2 ptr_scan:   pointer recurrence -> A,B,W[b,t,96], 4 batches/block
//  K3 stack_affine: stz' = A*stz + B*xvz, out = sum W*stz + ZO*pop
//     R7 fix: NO runtime-indexed local arrays (R6 put them in scratch ->
//     1.1 GB of scratch writes, 712 us). Two named buffers + unroll-by-2.
// B=128, T=256, D=256, NSTK=32.

#define NSTK 32
#define DDIM 256
#define ZO 1e-6f
#define EPSC 1e-8f
#define PEPS 1e-12f
#define CHUNK 32
#define MAXT 1024

__device__ __forceinline__ float elu_f(float c) {
    return (c > 0.f) ? c : expm1f(c);
}

// DPP cross-lane helpers (verified R4/R5)
__device__ __forceinline__ float dpp_xor1(float x) {
    return __int_as_float(__builtin_amdgcn_update_dpp(0, __float_as_int(x), 0xB1, 0xF, 0xF, true));
}
__device__ __forceinline__ float dpp_xor2(float x) {
    return __int_as_float(__builtin_amdgcn_update_dpp(0, __float_as_int(x), 0x4E, 0xF, 0xF, true));
}
__device__ __forceinline__ float dpp_halfmirror(float x) {
    return __int_as_float(__builtin_amdgcn_update_dpp(0, __float_as_int(x), 0x141, 0xF, 0xF, true));
}
__device__ __forceinline__ float dpp_mirror(float x) {
    return __int_as_float(__builtin_amdgcn_update_dpp(0, __float_as_int(x), 0x140, 0xF, 0xF, true));
}
__device__ __forceinline__ float rdlane(float v, int l) {
    return __int_as_float(__builtin_amdgcn_readlane(__float_as_int(v), l));
}

// ---------------- K1: fused gates + latch scan -> pop[B,T] ------------------
__launch_bounds__(256, 1)
__global__ void pop_fused_kernel(const float* __restrict__ x,
                                 const float* __restrict__ should_pop,
                                 const float* __restrict__ latch_enable,
                                 const float* __restrict__ latch_init,
                                 float* __restrict__ pop_out, int T) {
    const int b = blockIdx.x;
    const int tid = threadIdx.x;               // = d
    const int wave = tid >> 6, lane = tid & 63;
    __shared__ float part[256 * 66];           // [d][64 partials], pad->66
    __shared__ float red4[4][64];
    __shared__ float g_s[CHUNK];

    const float sp_d = should_pop[tid];
    const float le_d = latch_enable[tid];
    float a0 = sp_d * sp_d, a1 = le_d * le_d;
#pragma unroll
    for (int off = 32; off >= 1; off >>= 1) {
        a0 += __shfl_xor(a0, off, 64);
        a1 += __shfl_xor(a1, off, 64);
    }
    if (lane == 0) { red4[wave][0] = a0; red4[wave][1] = a1; }
    __syncthreads();
    const float an_sp = fmaxf(sqrtf(red4[0][0] + red4[1][0] + red4[2][0] + red4[3][0]), EPSC);
    const float an_le = fmaxf(sqrtf(red4[0][1] + red4[1][1] + red4[2][1] + red4[3][1]), EPSC);
    __syncthreads();

    float l = latch_init[(size_t)b * DDIM + tid];
    const float* xb = x + (size_t)b * T * DDIM + tid;
    const int p = tid & 63, dg = tid >> 6;     // reduce assignment

    for (int c = 0; c < T; c += CHUNK) {
        float xv[CHUNK];
#pragma unroll
        for (int i = 0; i < CHUNK; i++) xv[i] = xb[(size_t)(c + i) * DDIM];

        // ---- Phase A: g_t from x only ----
#pragma unroll
        for (int i = 0; i < CHUNK; i++) {
            part[tid * 66 + 2 * i] = le_d * xv[i];
            part[tid * 66 + 2 * i + 1] = xv[i] * xv[i];
        }
        __syncthreads();
        {
            float s0 = 0.f, s1 = 0.f, s2 = 0.f, s3 = 0.f;
#pragma unroll
            for (int k = 0; k < 64; k += 4) {
                s0 += part[(dg * 64 + k) * 66 + p];
                s1 += part[(dg * 64 + k + 1) * 66 + p];
                s2 += part[(dg * 64 + k + 2) * 66 + p];
                s3 += part[(dg * 64 + k + 3) * 66 + p];
            }
            red4[wave][p] = (s0 + s1) + (s2 + s3);
        }
        __syncthreads();
        if (tid < CHUNK) {
            const float d0 = red4[0][2 * tid] + red4[1][2 * tid] + red4[2][2 * tid] + red4[3][2 * tid];
            const float d1 = red4[0][2 * tid + 1] + red4[1][2 * tid + 1] + red4[2][2 * tid + 1] + red4[3][2 * tid + 1];
            g_s[tid] = elu_f(d0 / (an_le * fmaxf(sqrtf(d1), EPSC)));
        }
        __syncthreads();

        // ---- Phase B: latch updates + pop partials ----
#pragma unroll
        for (int i = 0; i < CHUNK; i++) {
            part[tid * 66 + 2 * i] = sp_d * l;       // latch ENTERING step c+i
            part[tid * 66 + 2 * i + 1] = l * l;
            l = fmaf(g_s[i], xv[i] - l, l);
        }
        __syncthreads();
        {
            float s0 = 0.f, s1 = 0.f, s2 = 0.f, s3 = 0.f;
#pragma unroll
            for (int k = 0; k < 64; k += 4) {
                s0 += part[(dg * 64 + k) * 66 + p];
                s1 += part[(dg * 64 + k + 1) * 66 + p];
                s2 += part[(dg * 64 + k + 2) * 66 + p];
                s3 += part[(dg * 64 + k + 3) * 66 + p];
            }
            red4[wave][p] = (s0 + s1) + (s2 + s3);
        }
        __syncthreads();
        if (tid < CHUNK) {
            const float d0 = red4[0][2 * tid] + red4[1][2 * tid] + red4[2][2 * tid] + red4[3][2 * tid];
            const float d1 = red4[0][2 * tid + 1] + red4[1][2 * tid + 1] + red4[2][2 * tid + 1] + red4[3][2 * tid + 1];
            pop_out[(size_t)b * T + c + tid] = elu_f(d0 / (an_sp * fmaxf(sqrtf(d1), EPSC)));
        }
        __syncthreads();   // protect part/red4 before next chunk
    }
}

// ---------------- K2: pointer recurrence, 4 batches per block ---------------
// coef layout per (b,t): [A[32] | B[32] | W[32]]
__launch_bounds__(64, 1)
__global__ void ptr_scan_kernel(const float* __restrict__ pop_arr,  // [B,T]
                                const float* __restrict__ sharpen_ptr,
                                float* __restrict__ coef,           // [B,T,96]
                                int T) {
    const int blk = blockIdx.x;
    const int tid = threadIdx.x;
    const int n = tid & 31;
    const int grp = tid >> 5;                  // 0/1
    const int bA = blk * 4 + grp;
    const int bB = blk * 4 + 2 + grp;
    const float sharpen = sharpen_ptr[0];
    const bool sharp5 = (sharpen == 5.0f);

    __shared__ float pops[4 * MAXT];
    for (int i = tid; i < 4 * T; i += 64) pops[i] = pop_arr[(size_t)blk * 4 * T + i];
    __syncthreads();
    const float* popA = pops + grp * T;
    const float* popB = pops + (2 + grp) * T;
    float* cfA = coef + (size_t)bA * T * 96;
    float* cfB = coef + (size_t)bB * T * 96;

    float uA = (n == 0) ? 1.0f : ZO, iA = 1.0f;
    float uB = uA, iB = 1.0f;

    for (int t = 0; t < T; t++) {
        const float poA = popA[t], poB = popB[t];
        const float psA = 1.0f - poA, psB = 1.0f - poB;
        const float upA = __shfl(uA, (n + 31) & 31, 32);
        const float upB = __shfl(uB, (n + 31) & 31, 32);
        const float unA = __shfl(uA, (n + 1) & 31, 32);
        const float unB = __shfl(uB, (n + 1) & 31, 32);
        const float rA = fmaf(psA, upA, poA * unA);
        const float rB = fmaf(psB, upB, poB * unB);
        const float qA = fmaxf(rA * iA, PEPS);
        const float qB = fmaxf(rB * iB, PEPS);
        float nuA, nuB;
        if (sharp5) {
            const float a2 = qA * qA, b2 = qB * qB;
            nuA = a2 * a2 * qA; nuB = b2 * b2 * qB;
        } else {
            nuA = exp2f(sharpen * log2f(qA));
            nuB = exp2f(sharpen * log2f(qB));
        }
        float sA = nuA, sB = nuB;
        sA += dpp_xor1(sA);       sB += dpp_xor1(sB);
        sA += dpp_xor2(sA);       sB += dpp_xor2(sB);
        sA += dpp_halfmirror(sA); sB += dpp_halfmirror(sB);
        sA += dpp_mirror(sA);     sB += dpp_mirror(sB);
        const float tA = (tid < 32) ? (rdlane(sA, 15) + rdlane(sA, 31))
                                    : (rdlane(sA, 47) + rdlane(sA, 63));
        const float tB = (tid < 32) ? (rdlane(sB, 15) + rdlane(sB, 31))
                                    : (rdlane(sB, 47) + rdlane(sB, 63));
        const float ivA = 1.0f / fmaxf(tA, EPSC);
        const float ivB = 1.0f / fmaxf(tB, EPSC);
        const float pA = uA * iA, ppA = upA * iA, pnA = nuA * ivA;
        const float pB = uB * iB, ppB = upB * iB, pnB = nuB * ivB;
        float* rowA = cfA + (size_t)t * 96;
        float* rowB = cfB + (size_t)t * 96;
        rowA[n]      = fmaf(-psA, ppA, fmaf(-poA, pA, 1.0f));  // A = 1-B-pop*p
        rowA[32 + n] = psA * ppA;                              // Bc = push*pp
        rowA[64 + n] = poA * pnA;                              // W = pop*pnew
        rowB[n]      = fmaf(-psB, ppB, fmaf(-poB, pB, 1.0f));
        rowB[32 + n] = psB * ppB;
        rowB[64 + n] = poB * pnB;
        uA = nuA; iA = ivA;
        uB = nuB; iB = ivB;
    }
}

// ---------------- K3: affine stack recurrence + readout ---------------------
// grid (D/16, B), 64 threads: 16 dsub x 4 ng (8 slots each). No LDS.
// All buffers are NAMED struct fields selected at COMPILE time (unroll-by-2)
// so they live in VGPRs, not scratch.
struct CoefBuf {
    float4 A0, A1, B0, B1, W0, W1;
    float xv, pv;
};

__launch_bounds__(64)
__global__ void stack_affine_kernel(const float* __restrict__ x,       // [B,T,D]
                                    const float* __restrict__ coef,    // [B,T,96]
                                    const float* __restrict__ pop_arr, // [B,T]
                                    float* __restrict__ out,           // [B,T,D]
                                    int T) {
    const int b = blockIdx.y;
    const int dtile = blockIdx.x;              // 0..15
    const int lane = threadIdx.x;
    const int dsub = lane & 15;
    const int ng = lane >> 4;                  // slots ng*8..ng*8+7

    const float* cfb = coef + (size_t)b * T * 96 + ng * 8;
    const float* xb = x + (size_t)b * T * DDIM + dtile * 16 + dsub;
    const float* popb = pop_arr + (size_t)b * T;
    float* ob = out + (size_t)b * T * DDIM + dtile * 16 + dsub;

    float stz[8];
#pragma unroll
    for (int i = 0; i < 8; i++) stz[i] = 0.f;   // st = ZO -> stz = 0

    CoefBuf u0, u1;

    auto ld = [&](int t, CoefBuf& u) {
        const float* c = cfb + (size_t)t * 96;
        u.A0 = *(const float4*)(c);
        u.A1 = *(const float4*)(c + 4);
        u.B0 = *(const float4*)(c + 32);
        u.B1 = *(const float4*)(c + 36);
        u.W0 = *(const float4*)(c + 64);
        u.W1 = *(const float4*)(c + 68);
        u.xv = xb[(size_t)t * DDIM];
        u.pv = popb[t];
    };

    auto step = [&](int t, CoefBuf& u) {
        const float xvz = u.xv - ZO;
        float acc;
        stz[0] = fmaf(u.A0.x, stz[0], u.B0.x * xvz); acc  = u.W0.x * stz[0];
        stz[1] = fmaf(u.A0.y, stz[1], u.B0.y * xvz); acc = fmaf(u.W0.y, stz[1], acc);
        stz[2] = fmaf(u.A0.z, stz[2], u.B0.z * xvz); acc = fmaf(u.W0.z, stz[2], acc);
        stz[3] = fmaf(u.A0.w, stz[3], u.B0.w * xvz); acc = fmaf(u.W0.w, stz[3], acc);
        stz[4] = fmaf(u.A1.x, stz[4], u.B1.x * xvz); acc = fmaf(u.W1.x, stz[4], acc);
        stz[5] = fmaf(u.A1.y, stz[5], u.B1.y * xvz); acc = fmaf(u.W1.y, stz[5], acc);
        stz[6] = fmaf(u.A1.z, stz[6], u.B1.z * xvz); acc = fmaf(u.W1.z, stz[6], acc);
        stz[7] = fmaf(u.A1.w, stz[7], u.B1.w * xvz); acc = fmaf(u.W1.w, stz[7], acc);
        const float popv = u.pv;
        acc += __shfl_xor(acc, 16, 64);
        acc += __shfl_xor(acc, 32, 64);
        if (ng == 0) ob[(size_t)t * DDIM] = fmaf(ZO, popv, acc);
    };

    ld(0, u0);
    if (T > 1) ld(1, u1);

    for (int t = 0; t < T; t += 2) {
        step(t, u0);
        if (t + 2 < T) ld(t + 2, u0);          // prefetch into freed buffer
        step(t + 1, u1);
        if (t + 3 < T) ld(t + 3, u1);
    }
}

// ---------------- Fallback: monolithic kernel (correct, slower) -------------
__launch_bounds__(256, 1)
__global__ void neuralstack_kernel(const float* __restrict__ x,
                                   const float* __restrict__ should_pop,
                                   const float* __restrict__ sharpen_ptr,
                                   const float* __restrict__ latch_enable,
                                   const float* __restrict__ latch_init,
                                   float* __restrict__ out,
                                   int T) {
    const int b = blockIdx.x;
    const int tid = threadIdx.x;
    const int wave = tid >> 6;
    const int lane = tid & 63;
    __shared__ float red[2][16];
    const float sp_d = should_pop[tid];
    const float le_d = latch_enable[tid];
    const float sharpen = sharpen_ptr[0];
    float latch = latch_init[(size_t)b * DDIM + tid];
    float a0 = sp_d * sp_d, a1 = le_d * le_d;
#pragma unroll
    for (int off = 32; off >= 1; off >>= 1) {
        a0 += __shfl_xor(a0, off, 64);
        a1 += __shfl_xor(a1, off, 64);
    }
    if (lane == 0) { red[0][wave * 4] = a0; red[0][wave * 4 + 1] = a1; }
    __syncthreads();
    const float an_sp = fmaxf(sqrtf(red[0][0] + red[0][4] + red[0][8] + red[0][12]), EPSC);
    const float an_le = fmaxf(sqrtf(red[0][1] + red[0][5] + red[0][9] + red[0][13]), EPSC);
    __syncthreads();
    float st[NSTK], ptr[NSTK];
#pragma unroll
    for (int n = 0; n < NSTK; n++) { st[n] = ZO; ptr[n] = (n == 0) ? 1.0f : ZO; }
    const float* xb = x + (size_t)b * T * DDIM + tid;
    float* ob = out + (size_t)b * T * DDIM + tid;
    const bool sharp5 = (sharpen == 5.0f);
    float inp = xb[0];
    for (int t = 0; t < T; t++) {
        const int tn = (t + 1 < T) ? (t + 1) : (T - 1);
        const float inp_next = xb[(size_t)tn * DDIM];
        float r0 = sp_d * latch, r1 = latch * latch, r2 = le_d * inp, r3 = inp * inp;
#pragma unroll
        for (int off = 32; off >= 1; off >>= 1) {
            r0 += __shfl_xor(r0, off, 64);
            r1 += __shfl_xor(r1, off, 64);
            r2 += __shfl_xor(r2, off, 64);
            r3 += __shfl_xor(r3, off, 64);
        }
        const int buf = t & 1;
        if (lane == 0) {
            red[buf][wave * 4] = r0; red[buf][wave * 4 + 1] = r1;
            red[buf][wave * 4 + 2] = r2; red[buf][wave * 4 + 3] = r3;
        }
        __syncthreads();
        const float s0 = red[buf][0] + red[buf][4] + red[buf][8] + red[buf][12];
        const float s1 = red[buf][1] + red[buf][5] + red[buf][9] + red[buf][13];
        const float s2 = red[buf][2] + red[buf][6] + red[buf][10] + red[buf][14];
        const float s3 = red[buf][3] + red[buf][7] + red[buf][11] + red[buf][15];
        const float pop = elu_f(s0 / (an_sp * fmaxf(sqrtf(s1), EPSC)));
        const float push = 1.0f - pop;
        const float g = elu_f(s2 / (an_le * fmaxf(sqrtf(s3), EPSC)));
        float q[NSTK];
#pragma unroll
        for (int n = 0; n < NSTK; n++) {
            const float pp = ptr[(n + NSTK - 1) & (NSTK - 1)];
            const float pn = ptr[(n + 1) & (NSTK - 1)];
            q[n] = fmaxf(push * pp + pop * pn, PEPS);
        }
        if (sharp5) {
#pragma unroll
            for (int n = 0; n < NSTK; n++) { const float v = q[n], v2 = v * v; q[n] = v2 * v2 * v; }
        } else {
#pragma unroll
            for (int n = 0; n < NSTK; n++) q[n] = exp2f(sharpen * log2f(q[n]));
        }
        float qa = 0.f, qb = 0.f, qc = 0.f, qd = 0.f;
#pragma unroll
        for (int n = 0; n < NSTK; n += 4) { qa += q[n]; qb += q[n+1]; qc += q[n+2]; qd += q[n+3]; }
        const float inv = 1.0f / fmaxf((qa + qb) + (qc + qd), EPSC);
        float sacc = 0.f;
#pragma unroll
        for (int n = 0; n < NSTK; n++) {
            const float pp = ptr[(n + NSTK - 1) & (NSTK - 1)];
            const float pc_ = ptr[n];
            const float ns = push * (st[n] + pp * (inp - st[n])) + pop * (st[n] + pc_ * (ZO - st[n]));
            st[n] = ns;
            sacc += ns * (q[n] * inv);
        }
#pragma unroll
        for (int n = 0; n < NSTK; n++) ptr[n] = q[n] * inv;
        ob[(size_t)t * DDIM] = pop * sacc;
        latch = fmaf(g, inp - latch, latch);
        inp = inp_next;
    }
}

extern "C" void kernel_launch(void* const* d_in, const int* in_sizes, int n_in,
                              void* d_out, int out_size, void* d_ws, size_t ws_size,
                              hipStream_t stream) {
    const float* x = (const float*)d_in[0];
    const float* should_pop = (const float*)d_in[1];
    const float* sharpen_ptr = (const float*)d_in[2];
    const float* latch_enable = (const float*)d_in[3];
    const float* latch_init = (const float*)d_in[4];
    float* out = (float*)d_out;

    const int D = in_sizes[1];                 // 256
    const int B = in_sizes[4] / D;             // 128
    const int T = in_sizes[0] / in_sizes[4];   // 256
    (void)n_in; (void)out_size;

    const size_t BT = (size_t)B * T;
    const size_t off_pop = 0;
    const size_t off_coef = BT;
    const size_t need_floats = off_coef + BT * 96;

    if (ws_size < need_floats * sizeof(float) || D != DDIM ||
        (T % CHUNK) != 0 || (B % 4) != 0 || T > MAXT || (T % 2) != 0) {
        neuralstack_kernel<<<B, 256, 0, stream>>>(x, should_pop, sharpen_ptr,
                                                  latch_enable, latch_init, out, T);
        return;
    }

    float* ws = (float*)d_ws;
    float* pop = ws + off_pop;
    float* coef = ws + off_coef;

    pop_fused_kernel<<<B, 256, 0, stream>>>(x, should_pop, latch_enable,
                                            latch_init, pop, T);
    ptr_scan_kernel<<<B / 4, 64, 0, stream>>>(pop, sharpen_ptr, coef, T);
    stack_affine_kernel<<<dim3(DDIM / 16, B), 64, 0, stream>>>(x, coef, pop, out, T);
}

// Round 8
// 283.192 us; speedup vs baseline: 3.1769x; 1.0888x over previous
//
#include <hip/hip_runtime.h>
#include <math.h>

// NeuralstackOnly (R8): 4-stage pipeline with XCD-affinity (b%8) swizzle
//  K0 gate4:     g[b,t] = elu(cos(latch_enable, x[b,t,:]))
//  K1 latch_pop: latch scan + pop[b,t] = elu(cos(should_pop, latch))
//                (block b -> XCD b%8; LDS transpose reduce, pad 65)
//  K2 ptr_scan:  pointer recurrence -> A,B,W coef[b,t,96]
//                (block blk handles b%8==blk%8; float4 pop prefetch)
//  K3 stack_affine: stz' = A*stz + B*xvz; out = sum W*stz + ZO*pop
//                (grid.x = b -> XCD b%8 reads coef from local L2; depth-4
//                 named-buffer prefetch, ~130 VGPR, no scratch)
// B=128, T=256, D=256, NSTK=32.

#define NSTK 32
#define DDIM 256
#define ZO 1e-6f
#define EPSC 1e-8f
#define PEPS 1e-12f
#define CHUNK 32
#define MAXT 1024

__device__ __forceinline__ float elu_f(float c) {
    return (c > 0.f) ? c : expm1f(c);
}

// DPP cross-lane helpers (verified R4-R7)
__device__ __forceinline__ float dpp_xor1(float x) {
    return __int_as_float(__builtin_amdgcn_update_dpp(0, __float_as_int(x), 0xB1, 0xF, 0xF, true));
}
__device__ __forceinline__ float dpp_xor2(float x) {
    return __int_as_float(__builtin_amdgcn_update_dpp(0, __float_as_int(x), 0x4E, 0xF, 0xF, true));
}
__device__ __forceinline__ float dpp_halfmirror(float x) {
    return __int_as_float(__builtin_amdgcn_update_dpp(0, __float_as_int(x), 0x141, 0xF, 0xF, true));
}
__device__ __forceinline__ float dpp_mirror(float x) {
    return __int_as_float(__builtin_amdgcn_update_dpp(0, __float_as_int(x), 0x140, 0xF, 0xF, true));
}
__device__ __forceinline__ float rdlane(float v, int l) {
    return __int_as_float(__builtin_amdgcn_readlane(__float_as_int(v), l));
}

// ---------------- K0: wave-per-t cosine gate (proven R3-R5) -----------------
__global__ void gate4_kernel(const float* __restrict__ vecs,   // [B,T,D]
                             const float* __restrict__ par,    // [D]
                             float* __restrict__ gout,         // [B,T]
                             int T) {
    const int b = blockIdx.y;
    const int t = blockIdx.x * 4 + (threadIdx.x >> 6);
    const int lane = threadIdx.x & 63;
    const float4 v = *(const float4*)(vecs + ((size_t)b * T + t) * DDIM + lane * 4);
    const float4 p = *(const float4*)(par + lane * 4);
    float r0 = v.x * p.x + v.y * p.y + v.z * p.z + v.w * p.w;
    float r1 = v.x * v.x + v.y * v.y + v.z * v.z + v.w * v.w;
    float r2 = p.x * p.x + p.y * p.y + p.z * p.z + p.w * p.w;
#pragma unroll
    for (int off = 32; off >= 1; off >>= 1) {
        r0 += __shfl_xor(r0, off, 64);
        r1 += __shfl_xor(r1, off, 64);
        r2 += __shfl_xor(r2, off, 64);
    }
    if (lane == 0) {
        const float c = r0 / (fmaxf(sqrtf(r2), EPSC) * fmaxf(sqrtf(r1), EPSC));
        gout[(size_t)b * T + t] = elu_f(c);
    }
}

// ---------------- K1: latch scan + pop gate, block per b --------------------
__launch_bounds__(256, 1)
__global__ void latch_pop_kernel(const float* __restrict__ x,
                                 const float* __restrict__ should_pop,
                                 const float* __restrict__ latch_init,
                                 const float* __restrict__ g,      // [B,T]
                                 float* __restrict__ pop_out,      // [B,T]
                                 int T) {
    const int b = blockIdx.x;
    const int tid = threadIdx.x;               // = d
    const int wave = tid >> 6, lane = tid & 63;
    __shared__ float part[256 * 65];           // pad 65: write bank-spread
    __shared__ float red4[4][64];

    const float sp_d = should_pop[tid];
    float a0 = sp_d * sp_d;
#pragma unroll
    for (int off = 32; off >= 1; off >>= 1) a0 += __shfl_xor(a0, off, 64);
    if (lane == 0) red4[wave][0] = a0;
    __syncthreads();
    const float an_sp = fmaxf(sqrtf(red4[0][0] + red4[1][0] + red4[2][0] + red4[3][0]), EPSC);
    __syncthreads();

    float l = latch_init[(size_t)b * DDIM + tid];
    const float* xb = x + (size_t)b * T * DDIM + tid;
    const float* gb = g + (size_t)b * T;
    const int p = tid & 63, dg = tid >> 6;

    for (int c = 0; c < T; c += CHUNK) {
        float xv[CHUNK], gv[CHUNK];
#pragma unroll
        for (int i = 0; i < CHUNK; i++) xv[i] = xb[(size_t)(c + i) * DDIM];
#pragma unroll
        for (int i = 0; i < CHUNK; i++) gv[i] = gb[c + i];   // uniform -> s_load
#pragma unroll
        for (int i = 0; i < CHUNK; i++) {
            part[tid * 65 + 2 * i] = sp_d * l;       // latch ENTERING step c+i
            part[tid * 65 + 2 * i + 1] = l * l;
            l = fmaf(gv[i], xv[i] - l, l);
        }
        __syncthreads();
        {
            float s0 = 0.f, s1 = 0.f, s2 = 0.f, s3 = 0.f;
#pragma unroll
            for (int k = 0; k < 64; k += 4) {
                s0 += part[(dg * 64 + k) * 65 + p];
                s1 += part[(dg * 64 + k + 1) * 65 + p];
                s2 += part[(dg * 64 + k + 2) * 65 + p];
                s3 += part[(dg * 64 + k + 3) * 65 + p];
            }
            red4[wave][p] = (s0 + s1) + (s2 + s3);
        }
        __syncthreads();
        if (tid < CHUNK) {
            const float d0 = red4[0][2 * tid] + red4[1][2 * tid] + red4[2][2 * tid] + red4[3][2 * tid];
            const float d1 = red4[0][2 * tid + 1] + red4[1][2 * tid + 1] + red4[2][2 * tid + 1] + red4[3][2 * tid + 1];
            pop_out[(size_t)b * T + c + tid] = elu_f(d0 / (an_sp * fmaxf(sqrtf(d1), EPSC)));
        }
        __syncthreads();
    }
}

// ---------------- K2: pointer recurrence, XCD-aligned b mapping -------------
// block blk (32 blocks) handles the 4 b's {base+8*sup+32*k}, base=blk%8 so
// coef[b] is written from XCD b%8. coef layout per (b,t): [A|B|W] 96 floats.
__launch_bounds__(64, 1)
__global__ void ptr_scan_kernel(const float* __restrict__ pop_arr,  // [B,T]
                                const float* __restrict__ sharpen_ptr,
                                float* __restrict__ coef,           // [B,T,96]
                                int T) {
    const int blk = blockIdx.x;
    const int tid = threadIdx.x;
    const int n = tid & 31;
    const int grp = tid >> 5;                  // 0/1
    const int base = blk & 7, sup = blk >> 3;
    const int b0 = base + 8 * sup;             // b%8 == blk%8 for all 4
    const int bA = b0 + 32 * grp;
    const int bB = b0 + 32 * (2 + grp);
    const float sharpen = sharpen_ptr[0];
    const bool sharp5 = (sharpen == 5.0f);

    __shared__ float pops[4 * MAXT];
    for (int i = tid; i < 4 * T; i += 64) {
        const int j = i / T, t = i - j * T;
        pops[i] = pop_arr[(size_t)(b0 + 32 * j) * T + t];
    }
    __syncthreads();
    const float* popA = pops + grp * T;
    const float* popB = pops + (2 + grp) * T;
    float* cfA = coef + (size_t)bA * T * 96;
    float* cfB = coef + (size_t)bB * T * 96;

    float uA = (n == 0) ? 1.0f : ZO, iA = 1.0f;
    float uB = uA, iB = 1.0f;

    auto stepAB = [&](int t, float poA, float poB) {
        const float psA = 1.0f - poA, psB = 1.0f - poB;
        const float upA = __shfl(uA, (n + 31) & 31, 32);
        const float upB = __shfl(uB, (n + 31) & 31, 32);
        const float unA = __shfl(uA, (n + 1) & 31, 32);
        const float unB = __shfl(uB, (n + 1) & 31, 32);
        const float rA = fmaf(psA, upA, poA * unA);
        const float rB = fmaf(psB, upB, poB * unB);
        const float qA = fmaxf(rA * iA, PEPS);
        const float qB = fmaxf(rB * iB, PEPS);
        float nuA, nuB;
        if (sharp5) {
            const float a2 = qA * qA, b2 = qB * qB;
            nuA = a2 * a2 * qA; nuB = b2 * b2 * qB;
        } else {
            nuA = exp2f(sharpen * log2f(qA));
            nuB = exp2f(sharpen * log2f(qB));
        }
        float sA = nuA, sB = nuB;
        sA += dpp_xor1(sA);       sB += dpp_xor1(sB);
        sA += dpp_xor2(sA);       sB += dpp_xor2(sB);
        sA += dpp_halfmirror(sA); sB += dpp_halfmirror(sB);
        sA += dpp_mirror(sA);     sB += dpp_mirror(sB);
        const float tA = (tid < 32) ? (rdlane(sA, 15) + rdlane(sA, 31))
                                    : (rdlane(sA, 47) + rdlane(sA, 63));
        const float tB = (tid < 32) ? (rdlane(sB, 15) + rdlane(sB, 31))
                                    : (rdlane(sB, 47) + rdlane(sB, 63));
        const float ivA = 1.0f / fmaxf(tA, EPSC);
        const float ivB = 1.0f / fmaxf(tB, EPSC);
        const float pA = uA * iA, ppA = upA * iA, pnA = nuA * ivA;
        const float pB = uB * iB, ppB = upB * iB, pnB = nuB * ivB;
        float* rowA = cfA + (size_t)t * 96;
        float* rowB = cfB + (size_t)t * 96;
        rowA[n]      = fmaf(-psA, ppA, fmaf(-poA, pA, 1.0f));  // A = 1-B-pop*p
        rowA[32 + n] = psA * ppA;                              // Bc = push*pp
        rowA[64 + n] = poA * pnA;                              // W = pop*pnew
        rowB[n]      = fmaf(-psB, ppB, fmaf(-poB, pB, 1.0f));
        rowB[32 + n] = psB * ppB;
        rowB[64 + n] = poB * pnB;
        uA = nuA; iA = ivA;
        uB = nuB; iB = ivB;
    };

    // pop values prefetched one 4-group ahead (LDS read off the serial chain)
    float4 a4 = *(const float4*)(popA);
    float4 b4 = *(const float4*)(popB);
    for (int t = 0; t < T; t += 4) {
        float4 a4n, b4n;
        if (t + 4 < T) {
            a4n = *(const float4*)(popA + t + 4);
            b4n = *(const float4*)(popB + t + 4);
        }
        stepAB(t + 0, a4.x, b4.x);
        stepAB(t + 1, a4.y, b4.y);
        stepAB(t + 2, a4.z, b4.z);
        stepAB(t + 3, a4.w, b4.w);
        a4 = a4n; b4 = b4n;
    }
}

// ---------------- K3: affine stack recurrence + readout ---------------------
// grid (B, D/16): blockIdx.x = b -> XCD b%8 (coef L2-local). 64 threads =
// 16 dsub x 4 ng (8 slots each). Depth-4 NAMED-buffer prefetch (no runtime-
// indexed locals -> no scratch; R6 lesson).
struct CoefBuf {
    float4 A0, A1, B0, B1, W0, W1;
    float xv, pv;
};

__launch_bounds__(64)
__global__ void stack_affine_kernel(const float* __restrict__ x,       // [B,T,D]
                                    const float* __restrict__ coef,    // [B,T,96]
                                    const float* __restrict__ pop_arr, // [B,T]
                                    float* __restrict__ out,           // [B,T,D]
                                    int T) {
    const int b = blockIdx.x;
    const int dtile = blockIdx.y;              // 0..15
    const int lane = threadIdx.x;
    const int dsub = lane & 15;
    const int ng = lane >> 4;                  // slots ng*8..ng*8+7

    const float* cfb = coef + (size_t)b * T * 96 + ng * 8;
    const float* xb = x + (size_t)b * T * DDIM + dtile * 16 + dsub;
    const float* popb = pop_arr + (size_t)b * T;
    float* ob = out + (size_t)b * T * DDIM + dtile * 16 + dsub;

    float stz[8];
#pragma unroll
    for (int i = 0; i < 8; i++) stz[i] = 0.f;   // st = ZO -> stz = 0

    CoefBuf u0, u1, u2, u3;

    auto ld = [&](int t, CoefBuf& u) {
        const float* c = cfb + (size_t)t * 96;
        u.A0 = *(const float4*)(c);
        u.A1 = *(const float4*)(c + 4);
        u.B0 = *(const float4*)(c + 32);
        u.B1 = *(const float4*)(c + 36);
        u.W0 = *(const float4*)(c + 64);
        u.W1 = *(const float4*)(c + 68);
        u.xv = xb[(size_t)t * DDIM];
        u.pv = popb[t];
    };

    auto step = [&](int t, CoefBuf& u) {
        const float xvz = u.xv - ZO;
        float acc;
        stz[0] = fmaf(u.A0.x, stz[0], u.B0.x * xvz); acc  = u.W0.x * stz[0];
        stz[1] = fmaf(u.A0.y, stz[1], u.B0.y * xvz); acc = fmaf(u.W0.y, stz[1], acc);
        stz[2] = fmaf(u.A0.z, stz[2], u.B0.z * xvz); acc = fmaf(u.W0.z, stz[2], acc);
        stz[3] = fmaf(u.A0.w, stz[3], u.B0.w * xvz); acc = fmaf(u.W0.w, stz[3], acc);
        stz[4] = fmaf(u.A1.x, stz[4], u.B1.x * xvz); acc = fmaf(u.W1.x, stz[4], acc);
        stz[5] = fmaf(u.A1.y, stz[5], u.B1.y * xvz); acc = fmaf(u.W1.y, stz[5], acc);
        stz[6] = fmaf(u.A1.z, stz[6], u.B1.z * xvz); acc = fmaf(u.W1.z, stz[6], acc);
        stz[7] = fmaf(u.A1.w, stz[7], u.B1.w * xvz); acc = fmaf(u.W1.w, stz[7], acc);
        const float popv = u.pv;
        acc += __shfl_xor(acc, 16, 64);
        acc += __shfl_xor(acc, 32, 64);
        if (ng == 0) ob[(size_t)t * DDIM] = fmaf(ZO, popv, acc);
    };

    ld(0, u0); ld(1, u1); ld(2, u2); ld(3, u3);

    for (int t = 0; t < T; t += 4) {
        step(t, u0);     if (t + 4 < T) ld(t + 4, u0);
        step(t + 1, u1); if (t + 5 < T) ld(t + 5, u1);
        step(t + 2, u2); if (t + 6 < T) ld(t + 6, u2);
        step(t + 3, u3); if (t + 7 < T) ld(t + 7, u3);
    }
}

// ---------------- Fallback: monolithic kernel (correct, slower) -------------
__launch_bounds__(256, 1)
__global__ void neuralstack_kernel(const float* __restrict__ x,
                                   const float* __restrict__ should_pop,
                                   const float* __restrict__ sharpen_ptr,
                                   const float* __restrict__ latch_enable,
                                   const float* __restrict__ latch_init,
                                   float* __restrict__ out,
                                   int T) {
    const int b = blockIdx.x;
    const int tid = threadIdx.x;
    const int wave = tid >> 6;
    const int lane = tid & 63;
    __shared__ float red[2][16];
    const float sp_d = should_pop[tid];
    const float le_d = latch_enable[tid];
    const float sharpen = sharpen_ptr[0];
    float latch = latch_init[(size_t)b * DDIM + tid];
    float a0 = sp_d * sp_d, a1 = le_d * le_d;
#pragma unroll
    for (int off = 32; off >= 1; off >>= 1) {
        a0 += __shfl_xor(a0, off, 64);
        a1 += __shfl_xor(a1, off, 64);
    }
    if (lane == 0) { red[0][wave * 4] = a0; red[0][wave * 4 + 1] = a1; }
    __syncthreads();
    const float an_sp = fmaxf(sqrtf(red[0][0] + red[0][4] + red[0][8] + red[0][12]), EPSC);
    const float an_le = fmaxf(sqrtf(red[0][1] + red[0][5] + red[0][9] + red[0][13]), EPSC);
    __syncthreads();
    float st[NSTK], ptr[NSTK];
#pragma unroll
    for (int n = 0; n < NSTK; n++) { st[n] = ZO; ptr[n] = (n == 0) ? 1.0f : ZO; }
    const float* xb = x + (size_t)b * T * DDIM + tid;
    float* ob = out + (size_t)b * T * DDIM + tid;
    const bool sharp5 = (sharpen == 5.0f);
    float inp = xb[0];
    for (int t = 0; t < T; t++) {
        const int tn = (t + 1 < T) ? (t + 1) : (T - 1);
        const float inp_next = xb[(size_t)tn * DDIM];
        float r0 = sp_d * latch, r1 = latch * latch, r2 = le_d * inp, r3 = inp * inp;
#pragma unroll
        for (int off = 32; off >= 1; off >>= 1) {
            r0 += __shfl_xor(r0, off, 64);
            r1 += __shfl_xor(r1, off, 64);
            r2 += __shfl_xor(r2, off, 64);
            r3 += __shfl_xor(r3, off, 64);
        }
        const int buf = t & 1;
        if (lane == 0) {
            red[buf][wave * 4] = r0; red[buf][wave * 4 + 1] = r1;
            red[buf][wave * 4 + 2] = r2; red[buf][wave * 4 + 3] = r3;
        }
        __syncthreads();
        const float s0 = red[buf][0] + red[buf][4] + red[buf][8] + red[buf][12];
        const float s1 = red[buf][1] + red[buf][5] + red[buf][9] + red[buf][13];
        const float s2 = red[buf][2] + red[buf][6] + red[buf][10] + red[buf][14];
        const float s3 = red[buf][3] + red[buf][7] + red[buf][11] + red[buf][15];
        const float pop = elu_f(s0 / (an_sp * fmaxf(sqrtf(s1), EPSC)));
        const float push = 1.0f - pop;
        const float g = elu_f(s2 / (an_le * fmaxf(sqrtf(s3), EPSC)));
        float q[NSTK];
#pragma unroll
        for (int n = 0; n < NSTK; n++) {
            const float pp = ptr[(n + NSTK - 1) & (NSTK - 1)];
            const float pn = ptr[(n + 1) & (NSTK - 1)];
            q[n] = fmaxf(push * pp + pop * pn, PEPS);
        }
        if (sharp5) {
#pragma unroll
            for (int n = 0; n < NSTK; n++) { const float v = q[n], v2 = v * v; q[n] = v2 * v2 * v; }
        } else {
#pragma unroll
            for (int n = 0; n < NSTK; n++) q[n] = exp2f(sharpen * log2f(q[n]));
        }
        float qa = 0.f, qb = 0.f, qc = 0.f, qd = 0.f;
#pragma unroll
        for (int n = 0; n < NSTK; n += 4) { qa += q[n]; qb += q[n+1]; qc += q[n+2]; qd += q[n+3]; }
        const float inv = 1.0f / fmaxf((qa + qb) + (qc + qd), EPSC);
        float sacc = 0.f;
#pragma unroll
        for (int n = 0; n < NSTK; n++) {
            const float pp = ptr[(n + NSTK - 1) & (NSTK - 1)];
            const float pc_ = ptr[n];
            const float ns = push * (st[n] + pp * (inp - st[n])) + pop * (st[n] + pc_ * (ZO - st[n]));
            st[n] = ns;
            sacc += ns * (q[n] * inv);
        }
#pragma unroll
        for (int n = 0; n < NSTK; n++) ptr[n] = q[n] * inv;
        ob[(size_t)t * DDIM] = pop * sacc;
        latch = fmaf(g, inp - latch, latch);
        inp = inp_next;
    }
}

extern "C" void kernel_launch(void* const* d_in, const int* in_sizes, int n_in,
                              void* d_out, int out_size, void* d_ws, size_t ws_size,
                              hipStream_t stream) {
    const float* x = (const float*)d_in[0];
    const float* should_pop = (const float*)d_in[1];
    const float* sharpen_ptr = (const float*)d_in[2];
    const float* latch_enable = (const float*)d_in[3];
    const float* latch_init = (const float*)d_in[4];
    float* out = (float*)d_out;

    const int D = in_sizes[1];                 // 256
    const int B = in_sizes[4] / D;             // 128
    const int T = in_sizes[0] / in_sizes[4];   // 256
    (void)n_in; (void)out_size;

    const size_t BT = (size_t)B * T;
    const size_t off_g = 0;
    const size_t off_pop = BT;
    const size_t off_coef = 2 * BT;
    const size_t need_floats = off_coef + BT * 96;

    if (ws_size < need_floats * sizeof(float) || D != DDIM || B != 128 ||
        (T % CHUNK) != 0 || (T % 4) != 0 || T < 8 || T > MAXT) {
        neuralstack_kernel<<<B, 256, 0, stream>>>(x, should_pop, sharpen_ptr,
                                                  latch_enable, latch_init, out, T);
        return;
    }

    float* ws = (float*)d_ws;
    float* g = ws + off_g;
    float* pop = ws + off_pop;
    float* coef = ws + off_coef;

    gate4_kernel<<<dim3(T / 4, B), 256, 0, stream>>>(x, latch_enable, g, T);
    latch_pop_kernel<<<B, 256, 0, stream>>>(x, should_pop, latch_init, g, pop, T);
    ptr_scan_kernel<<<B / 4, 64, 0, stream>>>(pop, sharpen_ptr, coef, T);
    stack_affine_kernel<<<dim3(B, DDIM / 16), 64, 0, stream>>>(x, coef, pop, out, T);
}